// Round 4
// baseline (801.980 us; speedup 1.0000x reference)
//
#include <hip/hip_runtime.h>
#include <hip/hip_bf16.h>

#define NN 100000
#define NE 3200000
#define NF 512
#define NH 16
#define NC 40
#define NB 782          // ceil(NN/128) buckets of 128 nodes
#define NBLK 512        // multisplit blocks
#define CHUNK 6250      // NE / NBLK

typedef __attribute__((ext_vector_type(4))) float f32x4;
typedef __attribute__((ext_vector_type(8))) short bf16x8;

static __device__ __forceinline__ unsigned short f2b(float f) {
    unsigned int u = __float_as_uint(f);
    u += 0x7FFFu + ((u >> 16) & 1u);   // round-to-nearest-even
    return (unsigned short)(u >> 16);
}
static __device__ __forceinline__ float b2f(unsigned short u) {
    return __uint_as_float(((unsigned int)u) << 16);
}

// ---------------- multisplit pass 1: per-block bucket histograms ----------------

__global__ void __launch_bounds__(256) k_mshist(const int* __restrict__ ei,
                                                int* __restrict__ histG) {
    __shared__ int h[NB];
    for (int i = threadIdx.x; i < NB; i += 256) h[i] = 0;
    __syncthreads();
    int b = blockIdx.x;
    int e0 = b * CHUNK, e1 = min(NE, e0 + CHUNK);
    for (int e = e0 + threadIdx.x; e < e1; e += 256)
        atomicAdd(&h[((unsigned)ei[NE + e]) >> 7], 1);
    __syncthreads();
    for (int i = threadIdx.x; i < NB; i += 256)
        histG[b * NB + i] = h[i];    // coalesced row write
}

// ---------------- pass 2: per-bucket scan over blocks ----------------

__global__ void __launch_bounds__(512) k_colscan(const int* __restrict__ histG,
                                                 int* __restrict__ ofsG,
                                                 int* __restrict__ bcnt) {
    __shared__ int sh[NBLK];
    int k = blockIdx.x;          // bucket
    int t = threadIdx.x;         // block index
    int v = histG[t * NB + k];
    sh[t] = v;
    __syncthreads();
    for (int off = 1; off < NBLK; off <<= 1) {
        int add = (t >= off) ? sh[t - off] : 0;
        __syncthreads();
        sh[t] += add;
        __syncthreads();
    }
    ofsG[k * NBLK + t] = sh[t] - v;   // exclusive, coalesced write
    if (t == NBLK - 1) bcnt[k] = sh[t];
}

// ---------------- pass 3: scan bucket totals ----------------

__global__ void k_bscan(const int* __restrict__ bcnt, int* __restrict__ bptr) {
    __shared__ int sh[1024];
    int t = threadIdx.x;
    int v = (t < NB) ? bcnt[t] : 0;
    sh[t] = v;
    __syncthreads();
    for (int off = 1; off < 1024; off <<= 1) {
        int add = (t >= off) ? sh[t - off] : 0;
        __syncthreads();
        sh[t] += add;
        __syncthreads();
    }
    if (t < NB) bptr[t] = sh[t] - v;
    if (t == 0) bptr[NB] = NE;
}

// ---------------- pass 4: scatter via LDS cursors (no global atomics) ----------------

__global__ void __launch_bounds__(256) k_msscatter(const int* __restrict__ ei,
                                                   const int* __restrict__ bptr,
                                                   const int* __restrict__ ofsG,
                                                   unsigned int* __restrict__ pairs) {
    __shared__ int lcur[NB];
    int b = blockIdx.x;
    for (int k = threadIdx.x; k < NB; k += 256)
        lcur[k] = bptr[k] + ofsG[k * NBLK + b];
    __syncthreads();
    int e0 = b * CHUNK, e1 = min(NE, e0 + CHUNK);
    for (int e = e0 + threadIdx.x; e < e1; e += 256) {
        unsigned int s = (unsigned int)ei[e];
        unsigned int d = (unsigned int)ei[NE + e];
        int pos = atomicAdd(&lcur[d >> 7], 1);
        pairs[pos] = s | ((d & 127u) << 17);
    }
}

// ---------------- per-bucket degree -> dinv ----------------

__global__ void __launch_bounds__(256) k_degb(const unsigned int* __restrict__ pairs,
                                              const int* __restrict__ bptr,
                                              float* __restrict__ dinv) {
    __shared__ int lcnt[128];
    int b = blockIdx.x;
    if (threadIdx.x < 128) lcnt[threadIdx.x] = 0;
    __syncthreads();
    int s0 = bptr[b], s1 = bptr[b + 1];
    for (int e = s0 + threadIdx.x; e < s1; e += 256)
        atomicAdd(&lcnt[pairs[e] >> 17], 1);
    __syncthreads();
    int node = b * 128 + threadIdx.x;
    if (threadIdx.x < 128 && node < NN)
        dinv[node] = rsqrtf((float)(lcnt[threadIdx.x] + 1));
}

// ---------------- W1 pack (per-lane MFMA B-fragment layout, f32 -> bf16) ----------------

__global__ void k_packW1(const float* __restrict__ W1, unsigned short* __restrict__ pack) {
    int idx = blockIdx.x * 256 + threadIdx.x;   // 16*64*8 = 8192 total
    int s = idx >> 9;
    int l = (idx >> 3) & 63;
    int e = idx & 7;
    int k = s * 32 + (l >> 4) * 8 + e;
    int col = l & 15;
    pack[idx] = f2b(W1[k * 16 + col]);
}

// ---------------- GEMM1: hs1 = bf16((X @ W1) * dinv[:,None]) ----------------

__global__ void __launch_bounds__(256) k_gemm1(const float* __restrict__ x,
                                               const unsigned short* __restrict__ wp,
                                               const float* __restrict__ dinv,
                                               unsigned short* __restrict__ hs1) {
    int wave = threadIdx.x >> 6;
    int l = threadIdx.x & 63;
    int m0 = blockIdx.x * 64 + wave * 16;
    if (m0 >= NN) return;                        // NN % 16 == 0
    int row = m0 + (l & 15);
    int krow = (l >> 4) * 8;
    const float* xr = x + (size_t)row * NF + krow;
    const unsigned short* wl = wp + l * 8;

    f32x4 acc = {0.f, 0.f, 0.f, 0.f};
#pragma unroll 4
    for (int s = 0; s < 16; ++s) {
        f32x4 xa = *(const f32x4*)(xr + s * 32);
        f32x4 xb = *(const f32x4*)(xr + s * 32 + 4);
        union { bf16x8 v; unsigned short u[8]; } a;
        a.u[0] = f2b(xa.x); a.u[1] = f2b(xa.y); a.u[2] = f2b(xa.z); a.u[3] = f2b(xa.w);
        a.u[4] = f2b(xb.x); a.u[5] = f2b(xb.y); a.u[6] = f2b(xb.z); a.u[7] = f2b(xb.w);
        bf16x8 b = *(const bf16x8*)(wl + s * 512);
        acc = __builtin_amdgcn_mfma_f32_16x16x32_bf16(a.v, b, acc, 0, 0, 0);
    }
    // C layout: col = l&15, row = (l>>4)*4 + r
#pragma unroll
    for (int r = 0; r < 4; ++r) {
        int orow = m0 + (l >> 4) * 4 + r;
        hs1[(size_t)orow * NH + (l & 15)] = f2b(acc[r] * dinv[orow]);
    }
}

// ---------------- layer-1 aggregation: per-bucket LDS accumulate ----------------
// acc[n][j] = hs[node][j] + sum_{src->node} hs[src][j];  r1 = bf16(relu(acc*di+b1)*di)

__global__ void __launch_bounds__(256) k_aggb1(const unsigned int* __restrict__ pairs,
                                               const int* __restrict__ bptr,
                                               const unsigned short* __restrict__ hs,
                                               const float* __restrict__ dinv,
                                               const float* __restrict__ b1,
                                               unsigned short* __restrict__ r1) {
    __shared__ float acc[128 * NH];
    __shared__ float sh_di[128];
    __shared__ float sh_b[NH];
    int b = blockIdx.x;
    int node0 = b * 128;
    int t = threadIdx.x;
    if (t < 128) sh_di[t] = (node0 + t < NN) ? dinv[node0 + t] : 0.0f;
    if (t < NH) sh_b[t] = b1[t];
    for (int i = t; i < 128 * NH; i += 256) {
        int node = node0 + (i >> 4);
        acc[i] = (node < NN) ? b2f(hs[(size_t)node * NH + (i & 15)]) : 0.0f;
    }
    __syncthreads();
    int s0 = bptr[b], s1 = bptr[b + 1];
    int j = t & 15;
    int ec = t >> 4;           // 16 edge slices
#pragma unroll 4
    for (int e = s0 + ec; e < s1; e += 16) {
        unsigned int v = pairs[e];
        int src = v & 0x1FFFFu;
        int ld = v >> 17;
        atomicAdd(&acc[ld * NH + j], b2f(hs[(size_t)src * NH + j]));
    }
    __syncthreads();
    for (int i = t; i < 128 * NH; i += 256) {
        int n = i >> 4;
        int node = node0 + n;
        if (node < NN) {
            float di = sh_di[n];
            float v = fmaxf(acc[i] * di + sh_b[i & 15], 0.0f) * di;
            r1[(size_t)node * NH + (i & 15)] = f2b(v);
        }
    }
}

// ---------------- layer-2 aggregation + classifier + log_softmax ----------------

__global__ void __launch_bounds__(256) k_aggb2(const unsigned int* __restrict__ pairs,
                                               const int* __restrict__ bptr,
                                               const unsigned short* __restrict__ rs,
                                               const float* __restrict__ dinv,
                                               const float* __restrict__ W2,
                                               const float* __restrict__ b2,
                                               float* __restrict__ out) {
    __shared__ float acc[128 * NH];
    __shared__ float sh_di[128];
    __shared__ float w[NH * NC];
    __shared__ float bb[NC];
    int b = blockIdx.x;
    int node0 = b * 128;
    int t = threadIdx.x;
    if (t < 128) sh_di[t] = (node0 + t < NN) ? dinv[node0 + t] : 0.0f;
    for (int i = t; i < NH * NC; i += 256) w[i] = W2[i];
    if (t < NC) bb[t] = b2[t];
    for (int i = t; i < 128 * NH; i += 256) {
        int node = node0 + (i >> 4);
        acc[i] = (node < NN) ? b2f(rs[(size_t)node * NH + (i & 15)]) : 0.0f;
    }
    __syncthreads();
    int s0 = bptr[b], s1 = bptr[b + 1];
    int j = t & 15;
    int ec = t >> 4;
#pragma unroll 4
    for (int e = s0 + ec; e < s1; e += 16) {
        unsigned int v = pairs[e];
        int src = v & 0x1FFFFu;
        int ld = v >> 17;
        atomicAdd(&acc[ld * NH + j], b2f(rs[(size_t)src * NH + j]));
    }
    __syncthreads();
    // epilogue: 2 threads per node, 20 classes each
    int n = t >> 1;
    int half = t & 1;
    int node = node0 + n;
    if (node < NN) {
        float di = sh_di[n];
        float z[NH];
#pragma unroll
        for (int k = 0; k < NH; ++k) z[k] = acc[n * NH + k] * di;
        float lg[20];
#pragma unroll
        for (int c0 = 0; c0 < 20; ++c0) {
            int c = half * 20 + c0;
            float s = bb[c];
#pragma unroll
            for (int k = 0; k < NH; ++k) s += z[k] * w[k * NC + c];
            lg[c0] = s;
        }
        float mx = lg[0];
#pragma unroll
        for (int c0 = 1; c0 < 20; ++c0) mx = fmaxf(mx, lg[c0]);
        mx = fmaxf(mx, __shfl_xor(mx, 1, 64));
        float sum = 0.f;
#pragma unroll
        for (int c0 = 0; c0 < 20; ++c0) sum += __expf(lg[c0] - mx);
        sum += __shfl_xor(sum, 1, 64);
        float lse = mx + __logf(sum);
        float* op = out + (size_t)node * NC + half * 20;
#pragma unroll
        for (int c0 = 0; c0 < 20; ++c0) op[c0] = lg[c0] - lse;
    }
}

// ---------------- launch ----------------

extern "C" void kernel_launch(void* const* d_in, const int* in_sizes, int n_in,
                              void* d_out, int out_size, void* d_ws, size_t ws_size,
                              hipStream_t stream) {
    const float* x  = (const float*)d_in[0];
    const int*   ei = (const int*)d_in[1];
    const float* W1 = (const float*)d_in[2];
    const float* b1 = (const float*)d_in[3];
    const float* W2 = (const float*)d_in[4];
    const float* b2 = (const float*)d_in[5];
    float* out = (float*)d_out;

    char* ws = (char*)d_ws;
    size_t off = 0;
    auto alloc = [&](size_t bytes) -> void* {
        void* p = ws + off;
        off += (bytes + 255) & ~(size_t)255;
        return p;
    };
    int* histG      = (int*)alloc((size_t)NBLK * NB * 4);
    int* ofsG       = (int*)alloc((size_t)NB * NBLK * 4);
    int* bcnt       = (int*)alloc((size_t)NB * 4);
    int* bptr       = (int*)alloc((size_t)(NB + 1) * 4);
    float* dinv     = (float*)alloc((size_t)NN * 4);
    unsigned short* w1p = (unsigned short*)alloc(16 * 64 * 8 * 2);
    unsigned int* pairs = (unsigned int*)alloc((size_t)NE * 4);
    unsigned short* h1  = (unsigned short*)alloc((size_t)NN * NH * 2);  // hs1 bf16
    unsigned short* r1  = (unsigned short*)alloc((size_t)NN * NH * 2);  // rs bf16

    k_packW1<<<32, 256, 0, stream>>>(W1, w1p);
    k_mshist<<<NBLK, 256, 0, stream>>>(ei, histG);
    k_colscan<<<NB, NBLK, 0, stream>>>(histG, ofsG, bcnt);
    k_bscan<<<1, 1024, 0, stream>>>(bcnt, bptr);
    k_msscatter<<<NBLK, 256, 0, stream>>>(ei, bptr, ofsG, pairs);
    k_degb<<<NB, 256, 0, stream>>>(pairs, bptr, dinv);
    k_gemm1<<<(NN + 63) / 64, 256, 0, stream>>>(x, w1p, dinv, h1);
    k_aggb1<<<NB, 256, 0, stream>>>(pairs, bptr, h1, dinv, b1, r1);
    k_aggb2<<<NB, 256, 0, stream>>>(pairs, bptr, r1, dinv, W2, b2, out);
}

// Round 5
// 248.544 us; speedup vs baseline: 3.2267x; 3.2267x over previous
//
#include <hip/hip_runtime.h>
#include <hip/hip_bf16.h>

#define NN 100000
#define NE 3200000
#define NF 512
#define NH 16
#define NC 40
#define NB 782          // ceil(NN/128) buckets of 128 nodes
#define CAP 5120        // max edges per bucket (mean 4096, std 64)
#define NBLK 512        // multisplit blocks
#define CHUNK 6250      // NE / NBLK

typedef __attribute__((ext_vector_type(4))) float f32x4;
typedef __attribute__((ext_vector_type(8))) short bf16x8;

static __device__ __forceinline__ unsigned short f2b(float f) {
    unsigned int u = __float_as_uint(f);
    u += 0x7FFFu + ((u >> 16) & 1u);   // round-to-nearest-even
    return (unsigned short)(u >> 16);
}
static __device__ __forceinline__ float b2f(unsigned short u) {
    return __uint_as_float(((unsigned int)u) << 16);
}

// ---------------- multisplit pass 1: per-block bucket histograms ----------------

__global__ void __launch_bounds__(256) k_mshist(const int* __restrict__ ei,
                                                int* __restrict__ histG) {
    __shared__ int h[NB];
    for (int i = threadIdx.x; i < NB; i += 256) h[i] = 0;
    __syncthreads();
    int b = blockIdx.x;
    int e0 = b * CHUNK, e1 = min(NE, e0 + CHUNK);
    for (int e = e0 + threadIdx.x; e < e1; e += 256)
        atomicAdd(&h[((unsigned)ei[NE + e]) >> 7], 1);
    __syncthreads();
    for (int i = threadIdx.x; i < NB; i += 256)
        histG[b * NB + i] = h[i];    // coalesced row write
}

// ---------------- pass 2: per-bucket scan over blocks ----------------

__global__ void __launch_bounds__(512) k_colscan(const int* __restrict__ histG,
                                                 int* __restrict__ ofsG,
                                                 int* __restrict__ bcnt) {
    __shared__ int sh[NBLK];
    int k = blockIdx.x;          // bucket
    int t = threadIdx.x;         // block index
    int v = histG[t * NB + k];
    sh[t] = v;
    __syncthreads();
    for (int off = 1; off < NBLK; off <<= 1) {
        int add = (t >= off) ? sh[t - off] : 0;
        __syncthreads();
        sh[t] += add;
        __syncthreads();
    }
    ofsG[k * NBLK + t] = sh[t] - v;   // exclusive, coalesced write
    if (t == NBLK - 1) bcnt[k] = sh[t];
}

// ---------------- pass 3: scan bucket totals ----------------

__global__ void k_bscan(const int* __restrict__ bcnt, int* __restrict__ bptr,
                        int* __restrict__ rowptr) {
    __shared__ int sh[1024];
    int t = threadIdx.x;
    int v = (t < NB) ? bcnt[t] : 0;
    sh[t] = v;
    __syncthreads();
    for (int off = 1; off < 1024; off <<= 1) {
        int add = (t >= off) ? sh[t - off] : 0;
        __syncthreads();
        sh[t] += add;
        __syncthreads();
    }
    if (t < NB) bptr[t] = sh[t] - v;
    if (t == 0) { bptr[NB] = NE; rowptr[NN] = NE; }
}

// ---------------- pass 4: scatter via LDS cursors (no global atomics) ----------------

__global__ void __launch_bounds__(256) k_msscatter(const int* __restrict__ ei,
                                                   const int* __restrict__ bptr,
                                                   const int* __restrict__ ofsG,
                                                   unsigned int* __restrict__ pairs) {
    __shared__ int lcur[NB];
    int b = blockIdx.x;
    for (int k = threadIdx.x; k < NB; k += 256)
        lcur[k] = bptr[k] + ofsG[k * NBLK + b];
    __syncthreads();
    int e0 = b * CHUNK, e1 = min(NE, e0 + CHUNK);
    for (int e = e0 + threadIdx.x; e < e1; e += 256) {
        unsigned int s = (unsigned int)ei[e];
        unsigned int d = (unsigned int)ei[NE + e];
        int pos = atomicAdd(&lcur[d >> 7], 1);
        pairs[pos] = s | ((d & 127u) << 17);
    }
}

// ---------------- per-bucket counting sort -> CSR (rowptr, dinv, ssrc) ----------------

__global__ void __launch_bounds__(256) k_bsort(const unsigned int* __restrict__ pairs,
                                               const int* __restrict__ bptr,
                                               int* __restrict__ rowptr,
                                               float* __restrict__ dinv,
                                               int* __restrict__ ssrc) {
    __shared__ unsigned int ein[CAP];
    __shared__ unsigned int srt[CAP];
    __shared__ int lcnt[128], lofs[128], lcur[128];
    int b = blockIdx.x;
    int s0 = bptr[b], s1 = bptr[b + 1];
    int n = s1 - s0;
    for (int i = threadIdx.x; i < n; i += 256) ein[i] = pairs[s0 + i];
    if (threadIdx.x < 128) lcnt[threadIdx.x] = 0;
    __syncthreads();
    for (int i = threadIdx.x; i < n; i += 256) atomicAdd(&lcnt[ein[i] >> 17], 1);
    __syncthreads();
    if (threadIdx.x < 128) lofs[threadIdx.x] = lcnt[threadIdx.x];
    __syncthreads();
    for (int off = 1; off < 128; off <<= 1) {
        int add = 0;
        if (threadIdx.x < 128 && threadIdx.x >= off) add = lofs[threadIdx.x - off];
        __syncthreads();
        if (threadIdx.x < 128) lofs[threadIdx.x] += add;
        __syncthreads();
    }
    if (threadIdx.x < 128) {
        int excl = lofs[threadIdx.x] - lcnt[threadIdx.x];
        lcur[threadIdx.x] = excl;
        int node = b * 128 + threadIdx.x;
        if (node < NN) {
            rowptr[node] = s0 + excl;
            dinv[node] = rsqrtf((float)(lcnt[threadIdx.x] + 1));
        }
    }
    __syncthreads();
    for (int i = threadIdx.x; i < n; i += 256) {
        unsigned int v = ein[i];
        int pos = atomicAdd(&lcur[v >> 17], 1);
        srt[pos] = v & 0x1FFFFu;
    }
    __syncthreads();
    for (int i = threadIdx.x; i < n; i += 256) ssrc[s0 + i] = (int)srt[i];
}

// ---------------- W1 pack (per-lane MFMA B-fragment layout, f32 -> bf16) ----------------
// idx = (s*64 + l)*8 + e  holds  W1[32*s + (l>>4)*8 + e][l&15]

__global__ void k_packW1(const float* __restrict__ W1, unsigned short* __restrict__ pack) {
    int idx = blockIdx.x * 256 + threadIdx.x;   // 16*64*8 = 8192 total
    int s = idx >> 9;
    int l = (idx >> 3) & 63;
    int e = idx & 7;
    int k = s * 32 + (l >> 4) * 8 + e;
    int col = l & 15;
    pack[idx] = f2b(W1[k * 16 + col]);
}

// ---------------- GEMM1: hs1 = bf16((X @ W1) * dinv[:,None]) ----------------

__global__ void __launch_bounds__(256) k_gemm1(const float* __restrict__ x,
                                               const unsigned short* __restrict__ wp,
                                               const float* __restrict__ dinv,
                                               unsigned short* __restrict__ hs1) {
    int wave = threadIdx.x >> 6;
    int l = threadIdx.x & 63;
    int m0 = blockIdx.x * 64 + wave * 16;
    if (m0 >= NN) return;                        // NN % 16 == 0
    int row = m0 + (l & 15);
    int krow = (l >> 4) * 8;
    const float* xr = x + (size_t)row * NF + krow;
    const unsigned short* wl = wp + l * 8;

    f32x4 acc = {0.f, 0.f, 0.f, 0.f};
#pragma unroll 4
    for (int s = 0; s < 16; ++s) {
        f32x4 xa = *(const f32x4*)(xr + s * 32);
        f32x4 xb = *(const f32x4*)(xr + s * 32 + 4);
        union { bf16x8 v; unsigned short u[8]; } a;
        a.u[0] = f2b(xa.x); a.u[1] = f2b(xa.y); a.u[2] = f2b(xa.z); a.u[3] = f2b(xa.w);
        a.u[4] = f2b(xb.x); a.u[5] = f2b(xb.y); a.u[6] = f2b(xb.z); a.u[7] = f2b(xb.w);
        bf16x8 b = *(const bf16x8*)(wl + s * 512);
        acc = __builtin_amdgcn_mfma_f32_16x16x32_bf16(a.v, b, acc, 0, 0, 0);
    }
    // C layout: col = l&15, row = (l>>4)*4 + r
#pragma unroll
    for (int r = 0; r < 4; ++r) {
        int orow = m0 + (l >> 4) * 4 + r;
        hs1[(size_t)orow * NH + (l & 15)] = f2b(acc[r] * dinv[orow]);
    }
}

// ---------------- layer-1 aggregation: one wave per node ----------------
// acc = hs[node] + sum hs[src];  r1 = bf16(relu(acc*di + b1)*di)

__global__ void __launch_bounds__(256) k_agg1(const unsigned short* __restrict__ hs,
                                              const int* __restrict__ rowptr,
                                              const int* __restrict__ ssrc,
                                              const float* __restrict__ dinv,
                                              const float* __restrict__ b1,
                                              unsigned short* __restrict__ r1) {
    int l = threadIdx.x & 63;
    int node = blockIdx.x * 4 + (threadIdx.x >> 6);
    int j = l & 15;
    int ec = l >> 4;
    float di = dinv[node];
    int s = rowptr[node];
    int e1 = rowptr[node + 1];
    float acc = (ec == 0) ? b2f(hs[(size_t)node * NH + j]) : 0.0f;
#pragma unroll 4
    for (int e = s + ec; e < e1; e += 4) {
        int src = ssrc[e];
        acc += b2f(hs[(size_t)src * NH + j]);
    }
    acc += __shfl_xor(acc, 16, 64);
    acc += __shfl_xor(acc, 32, 64);
    if (ec == 0) {
        float o = fmaxf(acc * di + b1[j], 0.0f) * di;
        r1[(size_t)node * NH + j] = f2b(o);
    }
}

// ---------------- layer-2 aggregation + classifier + log_softmax ----------------

__global__ void __launch_bounds__(256) k_agg2(const unsigned short* __restrict__ rs,
                                              const int* __restrict__ rowptr,
                                              const int* __restrict__ ssrc,
                                              const float* __restrict__ dinv,
                                              const float* __restrict__ W2,
                                              const float* __restrict__ b2,
                                              float* __restrict__ out) {
    __shared__ float w[NH * NC];
    __shared__ float bb[NC];
    int t = threadIdx.x;
    for (int i = t; i < NH * NC; i += 256) w[i] = W2[i];
    if (t < NC) bb[t] = b2[t];
    __syncthreads();
    int l = t & 63;
    int node = blockIdx.x * 4 + (t >> 6);
    int j = l & 15;
    int ec = l >> 4;
    float di = dinv[node];
    int s = rowptr[node];
    int e1 = rowptr[node + 1];
    float acc = (ec == 0) ? b2f(rs[(size_t)node * NH + j]) : 0.0f;
#pragma unroll 4
    for (int e = s + ec; e < e1; e += 4) {
        int src = ssrc[e];
        acc += b2f(rs[(size_t)src * NH + j]);
    }
    acc += __shfl_xor(acc, 16, 64);
    acc += __shfl_xor(acc, 32, 64);
    // lanes 0-15 hold z[j] = acc*di; broadcast to 40 class lanes
    float zv = acc * di;
    float lg = (l < NC) ? bb[l] : -1e30f;
#pragma unroll
    for (int k = 0; k < NH; ++k) {
        float zk = __shfl(zv, k, 64);
        if (l < NC) lg += zk * w[k * NC + l];
    }
    float mx = lg;
#pragma unroll
    for (int off = 1; off < 64; off <<= 1) mx = fmaxf(mx, __shfl_xor(mx, off, 64));
    float ex = (l < NC) ? __expf(lg - mx) : 0.0f;
    float sm = ex;
#pragma unroll
    for (int off = 1; off < 64; off <<= 1) sm += __shfl_xor(sm, off, 64);
    if (l < NC) out[(size_t)node * NC + l] = lg - mx - __logf(sm);
}

// ---------------- launch ----------------

extern "C" void kernel_launch(void* const* d_in, const int* in_sizes, int n_in,
                              void* d_out, int out_size, void* d_ws, size_t ws_size,
                              hipStream_t stream) {
    const float* x  = (const float*)d_in[0];
    const int*   ei = (const int*)d_in[1];
    const float* W1 = (const float*)d_in[2];
    const float* b1 = (const float*)d_in[3];
    const float* W2 = (const float*)d_in[4];
    const float* b2 = (const float*)d_in[5];
    float* out = (float*)d_out;

    char* ws = (char*)d_ws;
    size_t off = 0;
    auto alloc = [&](size_t bytes) -> void* {
        void* p = ws + off;
        off += (bytes + 255) & ~(size_t)255;
        return p;
    };
    int* histG      = (int*)alloc((size_t)NBLK * NB * 4);
    int* ofsG       = (int*)alloc((size_t)NB * NBLK * 4);
    int* bcnt       = (int*)alloc((size_t)NB * 4);
    int* bptr       = (int*)alloc((size_t)(NB + 1) * 4);
    int* rowptr     = (int*)alloc((size_t)(NN + 1) * 4);
    float* dinv     = (float*)alloc((size_t)NN * 4);
    unsigned short* w1p = (unsigned short*)alloc(16 * 64 * 8 * 2);
    unsigned int* pairs = (unsigned int*)alloc((size_t)NE * 4);
    int* ssrc       = (int*)alloc((size_t)NE * 4);
    unsigned short* h1  = (unsigned short*)alloc((size_t)NN * NH * 2);  // bf16 hs1
    unsigned short* r1  = (unsigned short*)alloc((size_t)NN * NH * 2);  // bf16 rs

    k_packW1<<<32, 256, 0, stream>>>(W1, w1p);
    k_mshist<<<NBLK, 256, 0, stream>>>(ei, histG);
    k_colscan<<<NB, NBLK, 0, stream>>>(histG, ofsG, bcnt);
    k_bscan<<<1, 1024, 0, stream>>>(bcnt, bptr, rowptr);
    k_msscatter<<<NBLK, 256, 0, stream>>>(ei, bptr, ofsG, pairs);
    k_bsort<<<NB, 256, 0, stream>>>(pairs, bptr, rowptr, dinv, ssrc);
    k_gemm1<<<(NN + 63) / 64, 256, 0, stream>>>(x, w1p, dinv, h1);
    k_agg1<<<NN / 4, 256, 0, stream>>>(h1, rowptr, ssrc, dinv, b1, r1);
    k_agg2<<<NN / 4, 256, 0, stream>>>(r1, rowptr, ssrc, dinv, W2, b2, out);
}